// Round 7
// baseline (240.992 us; speedup 1.0000x reference)
//
#include <hip/hip_runtime.h>
#include <hip/hip_bf16.h>

// MultiHeadAttention: N=2048, H=16, D=128. f32 in, f32 out, int32 mask.
// R11: (a) REVERT proj to R9 LDS version (R10's global-W proj2 regressed
// +16us; prediction didn't match -> wrong theory, reverted on evidence).
// (b) attn: main loop had 24 wave-b128 LDS ops/wave-iter = ~50% of the
// 4600cy per-iter wall (MfmaUtil 23%, grid-capped 8 waves/CU). The LDS
// staging doesn't cut L2 traffic (tiles are read once from global either
// way) - it only adds ds_write+ds_read. So: NO LDS, NO barriers in main
// loop. Q-frags reg-double-buffered (prefetched 1 tile = ~1900cy ahead);
// V-frags loaded at compute top, covered by reg-only QK + softmax; ig-wave
// pairs read identical rows -> L1 2x reuse. Epilogue uses a dedicated 33KB
// LDS buffer (2 barriers total, was 33).
// zero/maskpack/final2 unchanged from R9.

#define HN 16
#define NN 2048
#define DD 128

typedef __attribute__((ext_vector_type(8))) short short8;    // MFMA A/B frag
typedef __attribute__((ext_vector_type(4))) short short4v;
typedef __attribute__((ext_vector_type(4))) float float4v;   // 16x16 C/D frag
typedef __attribute__((ext_vector_type(16))) float f32x16;   // 32x32 C/D frag
typedef __attribute__((ext_vector_type(4))) unsigned int uint4v;

#define CROW(r) ((((r) & 3)) + 8 * ((r) >> 2))   // 32x32 C/D row for reg r

__device__ inline unsigned short f2bf(float f) {
    unsigned int u = __builtin_bit_cast(unsigned int, f);
    unsigned int r = (u + 0x7fffu + ((u >> 16) & 1u)) >> 16;  // RNE
    return (unsigned short)r;
}

// packed f32x2 -> bf16x2 (RNE), gfx950 v_cvt_pk_bf16_f32
__device__ inline unsigned int cvtpk(float lo, float hi) {
    unsigned int w;
    asm("v_cvt_pk_bf16_f32 %0, %1, %2" : "=v"(w) : "v"(lo), "v"(hi));
    return w;
}

// exchange lane-halves: x' = {lo: x, hi: y from lane-32};
//                       y' = {lo: x from lane+32, hi: y}
__device__ inline void plswap(unsigned int& x, unsigned int& y) {
#if __has_builtin(__builtin_amdgcn_permlane32_swap)
    typedef int int2v __attribute__((ext_vector_type(2)));
    int2v r = __builtin_amdgcn_permlane32_swap((int)x, (int)y, false, false);
    x = (unsigned int)r[0];
    y = (unsigned int)r[1];
#else
    const unsigned int sx = (unsigned int)__shfl_xor((int)x, 32);
    const unsigned int sy = (unsigned int)__shfl_xor((int)y, 32);
    const bool hiHalf = (threadIdx.x & 32) != 0;
    const unsigned int nx = hiHalf ? sy : x;
    const unsigned int ny = hiHalf ? y : sx;
    x = nx; y = ny;
#endif
}

// 8 contiguous f32 -> bf16 MFMA frag
__device__ inline short8 ld_bf8(const float* __restrict__ p) {
    const float4v a = *(const float4v*)p;
    const float4v b = *(const float4v*)(p + 4);
    short8 r;
    r[0] = (short)f2bf(a[0]); r[1] = (short)f2bf(a[1]);
    r[2] = (short)f2bf(a[2]); r[3] = (short)f2bf(a[3]);
    r[4] = (short)f2bf(b[0]); r[5] = (short)f2bf(b[1]);
    r[6] = (short)f2bf(b[2]); r[7] = (short)f2bf(b[3]);
    return r;
}

// two ds_read_b64 frag load (for odd-pitch LDS arrays; needs 8B align)
__device__ inline short8 ld2x4(const unsigned short* p) {
    const short4v lo = *(const short4v*)p;
    const short4v hi = *(const short4v*)(p + 4);
    short8 r;
    r[0] = lo[0]; r[1] = lo[1]; r[2] = lo[2]; r[3] = lo[3];
    r[4] = hi[0]; r[5] = hi[1]; r[6] = hi[2]; r[7] = hi[3];
    return r;
}

__global__ void sentinel_kernel(float* out, int n) {
    int i = blockIdx.x * 256 + threadIdx.x;
    if (i < n) out[i] = 2.0f;
}

__global__ __launch_bounds__(256) void zero_kernel(float* __restrict__ out, int n) {
    const int i4 = blockIdx.x * 256 + threadIdx.x;
    if (i4 * 4 + 3 < n) {
        *(float4v*)(out + i4 * 4) = float4v{0.f, 0.f, 0.f, 0.f};
    } else {
        for (int i = i4 * 4; i < n; i++) out[i] = 0.f;
    }
}

// ---------------------------------------------------------------------------
// Kernel M: pack mask[2048][2048] int32 into bits: mb[i][w] covers
// j = w*64 + bit. One wave per 64-bit word via __ballot.
// ---------------------------------------------------------------------------
__global__ __launch_bounds__(256) void maskpack_kernel(
    const int* __restrict__ mask,
    unsigned long long* __restrict__ mb)
{
    const int word = blockIdx.x * 4 + (threadIdx.x >> 6);
    const int lane = threadIdx.x & 63;
    const int i = word >> 5;   // row
    const int w = word & 31;   // 64-col word within row
    const int mv = mask[(size_t)i * NN + w * 64 + lane];
    const unsigned long long b = __ballot(mv != 0);
    if (lane == 0) mb[word] = b;
}

// ---------------------------------------------------------------------------
// Kernel A: projections (R9 version). grid = (32 row-tiles, 16 heads, 3).
// t<2: qp/kp row-major [n][d].  t==2: vpT [d][n] via operand swap.
// ---------------------------------------------------------------------------
__global__ __launch_bounds__(256) void proj_kernel(
    const float* __restrict__ q,
    const float* __restrict__ k,
    const float* __restrict__ v,
    const float* __restrict__ Qw,
    const float* __restrict__ Kw,
    const float* __restrict__ Vw,
    unsigned short* __restrict__ ws)
{
    __shared__ __align__(16) unsigned short Wt[128 * 132];  // Wt[e][d] = bf16(W[d][e])
    const int t = blockIdx.z, h = blockIdx.y, rb = blockIdx.x;
    const int tid = threadIdx.x;
    const float* in = (t == 0) ? q : ((t == 1) ? k : v);
    const float* W  = ((t == 0) ? Qw : ((t == 1) ? Kw : Vw)) + h * DD * DD;
    unsigned short* out = ws + (size_t)t * (HN * NN * DD) + (size_t)h * (NN * DD);

    for (int idx2 = tid * 2; idx2 < DD * DD; idx2 += 512) {
        const int d = idx2 >> 7, e = idx2 & 127;
        const float2 w2 = *(const float2*)(W + idx2);
        Wt[(e + 0) * 132 + d] = f2bf(w2.x);
        Wt[(e + 1) * 132 + d] = f2bf(w2.y);
    }
    __syncthreads();

    const int wave = tid >> 6, lane = tid & 63;
    const int quad = lane >> 4, l16 = lane & 15;
    const int row0 = rb * 64 + wave * 16;   // token tile base for this wave

    float4v acc[8];
    for (int c = 0; c < 8; c++) acc[c] = {0.f, 0.f, 0.f, 0.f};

    if (t < 2) {
        // D[token][e]: A = input rows, B = Wt rows
        for (int kk = 0; kk < 4; kk++) {
            const short8 a = ld_bf8(in + (size_t)(row0 + l16) * DD + kk * 32 + quad * 8);
            for (int c = 0; c < 8; c++) {
                const short8 b = ld2x4(&Wt[(c * 16 + l16) * 132 + kk * 32 + quad * 8]);
                acc[c] = __builtin_amdgcn_mfma_f32_16x16x32_bf16(a, b, acc[c], 0, 0, 0);
            }
        }
        for (int c = 0; c < 8; c++)
            for (int r = 0; r < 4; r++)
                out[(size_t)(row0 + quad * 4 + r) * DD + c * 16 + l16] = f2bf(acc[c][r]);
    } else {
        // D[e][token] = vpT: A = Wt rows (Wv^T), B = v rows; same loads, swapped
        for (int kk = 0; kk < 4; kk++) {
            const short8 bv = ld_bf8(in + (size_t)(row0 + l16) * DD + kk * 32 + quad * 8);
            for (int c = 0; c < 8; c++) {
                const short8 aw = ld2x4(&Wt[(c * 16 + l16) * 132 + kk * 32 + quad * 8]);
                acc[c] = __builtin_amdgcn_mfma_f32_16x16x32_bf16(aw, bv, acc[c], 0, 0, 0);
            }
        }
        for (int c = 0; c < 8; c++)
            for (int r = 0; r < 4; r++)
                out[(size_t)(c * 16 + quad * 4 + r) * NN + row0 + l16] = f2bf(acc[c][r]);
    }
}

// ---------------------------------------------------------------------------
// Kernel B: flash attention, static-max softmax, 32x32x16 MFMA.
// grid = (32 i-tiles, 16 heads), 4 waves: wave = (ig = i-half, h2 = j-half).
// MAIN LOOP: no LDS, no barriers. Q reg-double-buffered (1-tile prefetch),
// V loaded per-compute (covered by reg-only QK + softmax), P in regs (T12).
// ---------------------------------------------------------------------------
__global__ __launch_bounds__(256, 2) void attn_kernel(
    unsigned short* __restrict__ ws,
    const unsigned long long* __restrict__ mb)
{
    __shared__ __align__(16) float obuf[8192];   // epilogue partial-O combine
    __shared__ float lbuf[192];                  // epilogue row sums / inv

    const int h = blockIdx.y, ib = blockIdx.x;
    const int tid = threadIdx.x;
    const int wave = tid >> 6, lane = tid & 63;
    const int ig = wave >> 1;        // i-group: 0 -> rows 0..31, 1 -> 32..63
    const int h2 = wave & 1;         // j-half of each 64-j tile
    const int l31 = lane & 31;
    const int hi = lane >> 5;        // lane half

    const unsigned short* qp  = ws + (size_t)h * (NN * DD);
    const unsigned short* kp  = ws + (size_t)(HN * NN * DD) + (size_t)h * (NN * DD);
    const unsigned short* vpT = ws + (size_t)(2 * HN * NN * DD) + (size_t)h * (NN * DD);
    unsigned short* ao = ws + (size_t)(3 * HN * NN * DD);  // [N][H*D]

    const int i0 = ib * 64;
    const float scale = 0.022097086912079612f;  // 1/sqrt(2048)

    // kp B-frags (B[k=d][n=i], lane&31 = i): loaded once, reused all iters.
    short8 kpf[8];
    {
        const int row = i0 + ig * 32 + l31;
#pragma unroll
        for (int kk = 0; kk < 8; kk++)
            kpf[kk] = *(const short8*)(kp + (size_t)row * DD + kk * 16 + hi * 8);
    }

    f32x16 o[4];
#pragma unroll
    for (int dt = 0; dt < 4; dt++)
#pragma unroll
        for (int r = 0; r < 16; r++) o[dt][r] = 0.f;
    float lacc = 0.f;

    // Q-frag register buffers (A-operand rows = this wave's j-half rows).
    short8 qfA[8], qfB[8];

#define QLOAD(QF, J0) do {                                                      \
        _Pragma("unroll")                                                       \
        for (int kk = 0; kk < 8; kk++)                                          \
            QF[kk] = *(const short8*)(qp + (size_t)((J0) + h2 * 32 + l31) * DD  \
                                      + kk * 16 + hi * 8);                      \
    } while (0)

    // Per-iteration compute using Q-frags in QF, tile column jt.
    // T[j][i] = sum_d qp[j][d]*kp[i][d]: A = qf (regs), B = kpf (regs).
    // C/D: col = lane&31 = i, row j = CROW(r) + 4*hi (+ h2*32 in tile).
    auto COMPUTE = [&](const short8 (&qf)[8], int jt) {
        // V B-frags straight from global; consumed after QK+softmax (~200cy).
        short8 vf0[4], vf1[4];
#pragma unroll
        for (int dt = 0; dt < 4; dt++)
            vf0[dt] = *(const short8*)(vpT + (size_t)(dt * 32 + l31) * NN
                                       + jt * 64 + h2 * 32 + hi * 8);
#pragma unroll
        for (int dt = 0; dt < 4; dt++)
            vf1[dt] = *(const short8*)(vpT + (size_t)(dt * 32 + l31) * NN
                                       + jt * 64 + h2 * 32 + 16 + hi * 8);
        const unsigned long long mrow = mb[(size_t)(i0 + ig * 32 + l31) * 32 + jt];
        const unsigned int m2 = (unsigned int)(mrow >> (h2 * 32 + hi * 4));

        f32x16 s;
#pragma unroll
        for (int r = 0; r < 16; r++) s[r] = 0.f;
#pragma unroll
        for (int kk = 0; kk < 8; kk++)
            s = __builtin_amdgcn_mfma_f32_32x32x16_bf16(qf[kk], kpf[kk], s, 0, 0, 0);

        // static-max softmax: p = exp(s*scale - 5) (masked -> exp(-50) ~ 0)
#pragma unroll
        for (int r = 0; r < 16; r++) {
            const float x = ((m2 >> CROW(r)) & 1u) ? fmaf(s[r], scale, -5.0f) : -50.0f;
            s[r] = __expf(x);
        }
        // row-sum over this j-tile for denominator (i = lane&31)
        float ls = (((s[0] + s[1]) + (s[2] + s[3])) + ((s[4] + s[5]) + (s[6] + s[7])))
                 + (((s[8] + s[9]) + (s[10] + s[11])) + ((s[12] + s[13]) + (s[14] + s[15])));
        ls += __shfl_xor(ls, 32);
        lacc += ls;

        // T12 repack: P -> two PV A-frags (lane = i, k = j), zero LDS.
        short8 pa[2];
#pragma unroll
        for (int ks = 0; ks < 2; ks++) {
            const int b = ks * 8;
            unsigned int x0 = cvtpk(s[b + 0], s[b + 1]);
            unsigned int y0 = cvtpk(s[b + 4], s[b + 5]);
            unsigned int x1 = cvtpk(s[b + 2], s[b + 3]);
            unsigned int y1 = cvtpk(s[b + 6], s[b + 7]);
            plswap(x0, y0);   // x0 -> e0e1 (lo j0j1 / hi j8j9), y0 -> e4e5
            plswap(x1, y1);   // x1 -> e2e3, y1 -> e6e7
            uint4v w; w[0] = x0; w[1] = x1; w[2] = y0; w[3] = y1;
            pa[ks] = __builtin_bit_cast(short8, w);
        }

        // O[i][d] += P · vp
#pragma unroll
        for (int dt = 0; dt < 4; dt++)
            o[dt] = __builtin_amdgcn_mfma_f32_32x32x16_bf16(pa[0], vf0[dt], o[dt], 0, 0, 0);
#pragma unroll
        for (int dt = 0; dt < 4; dt++)
            o[dt] = __builtin_amdgcn_mfma_f32_32x32x16_bf16(pa[1], vf1[dt], o[dt], 0, 0, 0);
    };

    // Software pipeline: Q for tile jt+1 always in flight; no barriers.
    QLOAD(qfA, 0);
#pragma unroll 1
    for (int jt = 0; jt < 32; jt += 2) {
        QLOAD(qfB, (jt + 1) * 64);
        COMPUTE(qfA, jt);
        QLOAD(qfA, (((jt + 2) & 31)) * 64);   // wraps to 0 on last iter (harmless)
        COMPUTE(qfB, jt + 1);
    }
#undef QLOAD

    // Epilogue: combine partner-wave partials (same ig, other j-half) via LDS,
    // normalize, store.
    if (h2 == 1) {
#pragma unroll
        for (int dt = 0; dt < 4; dt++)
#pragma unroll
            for (int r = 0; r < 16; r++)
                obuf[(((ig * 2 + hi) * 4 + dt) * 16 + r) * 32 + l31] = o[dt][r];
        if (hi == 0) lbuf[ig * 32 + l31] = lacc;
    }
    __syncthreads();
    if (h2 == 0) {
        const float lt = lacc + lbuf[ig * 32 + l31];
        const float inv = (lt > 0.f) ? (1.0f / lt) : 0.f;
        if (hi == 0) lbuf[64 + ig * 32 + l31] = inv;  // same-wave RAW, lgkm-ordered
#pragma unroll
        for (int dt = 0; dt < 4; dt++)
#pragma unroll
            for (int r = 0; r < 16; r++) {
                const int row = CROW(r) + hi * 4;     // i_local 0..31
                const float val = (o[dt][r] + obuf[(((ig * 2 + hi) * 4 + dt) * 16 + r) * 32 + l31])
                                  * lbuf[64 + ig * 32 + row];
                ao[(size_t)(i0 + ig * 32 + row) * (HN * DD) + h * DD + dt * 32 + l31] = f2bf(val);
            }
    }
}

// ---------------------------------------------------------------------------
// Kernel C: final GEMM [2048,2048]x[2048,128] -> f32, K-split x4.
// grid = (32 i, 4 e, 4 ks) = 512 blocks (2/CU). Whole 512-K `last` slice
// staged once (pitch 516: bank stride 2, b64-pair reads conflict-free);
// ONE barrier; 8 unrolled barrier-free MFMA iters; atomicAdd to zeroed out.
// ---------------------------------------------------------------------------
__global__ __launch_bounds__(256) void final2_kernel(
    const unsigned short* __restrict__ ao,
    const float* __restrict__ last,
    float* __restrict__ outp)
{
    __shared__ __align__(16) unsigned short lt[32 * 516];  // [e_local][k_local]
    const int tid = threadIdx.x;
    const int wave = tid >> 6, lane = tid & 63;
    const int quad = lane >> 4, l16 = lane & 15;
    const int i0 = blockIdx.x * 64;
    const int e0 = blockIdx.y * 32;
    const int k0 = blockIdx.z * 512;

    // stage last[k0..+512][e0..+32] transposed -> lt[e][k] bf16
#pragma unroll
    for (int idx2 = tid * 2; idx2 < 512 * 32; idx2 += 512) {
        const int kk = idx2 >> 5, e = idx2 & 31;
        const float2 w2 = *(const float2*)(last + (size_t)(k0 + kk) * DD + e0 + e);
        lt[(e + 0) * 516 + kk] = f2bf(w2.x);
        lt[(e + 1) * 516 + kk] = f2bf(w2.y);
    }
    __syncthreads();

    float4v acc[2];
    acc[0] = {0.f, 0.f, 0.f, 0.f};
    acc[1] = {0.f, 0.f, 0.f, 0.f};

    const unsigned short* arow = ao + (size_t)(i0 + wave * 16 + l16) * (HN * DD) + k0;

#pragma unroll
    for (int kb = 0; kb < 8; kb++) {
#pragma unroll
        for (int ks = 0; ks < 2; ks++) {
            const short8 a = *(const short8*)(arow + kb * 64 + ks * 32 + quad * 8);
#pragma unroll
            for (int dc = 0; dc < 2; dc++) {
                const short8 b = ld2x4(&lt[(dc * 16 + l16) * 516 + kb * 64 + ks * 32 + quad * 8]);
                acc[dc] = __builtin_amdgcn_mfma_f32_16x16x32_bf16(a, b, acc[dc], 0, 0, 0);
            }
        }
    }

#pragma unroll
    for (int r = 0; r < 4; r++)
#pragma unroll
        for (int dc = 0; dc < 2; dc++)
            atomicAdd(&outp[(size_t)(i0 + wave * 16 + quad * 4 + r) * DD + e0 + dc * 16 + l16],
                      acc[dc][r]);
}

extern "C" void kernel_launch(void* const* d_in, const int* in_sizes, int n_in,
                              void* d_out, int out_size, void* d_ws, size_t ws_size,
                              hipStream_t stream)
{
    const float* q    = (const float*)d_in[0];
    const float* k    = (const float*)d_in[1];
    const float* v    = (const float*)d_in[2];
    const int*   mask = (const int*)d_in[3];
    const float* Qw   = (const float*)d_in[4];
    const float* Kw   = (const float*)d_in[5];
    const float* Vw   = (const float*)d_in[6];
    const float* last = (const float*)d_in[7];
    unsigned short* ws  = (unsigned short*)d_ws;
    float* out = (float*)d_out;

    // ws (bf16): qp[16*2048*128] | kp[...] | vpT[16][128][2048] | ao[2048][2048]
    //            | mb[2048][32] u64 (bitpacked mask)
    const size_t shorts_main = (size_t)4 * HN * NN * DD;   // qp+kp+vpT+ao
    const size_t mb_bytes = (size_t)NN * (NN / 64) * 8;
    const size_t needed = shorts_main * sizeof(unsigned short) + mb_bytes;
    if (ws_size < needed) {
        sentinel_kernel<<<(out_size + 255) / 256, 256, 0, stream>>>(out, out_size);
        return;
    }
    unsigned long long* mb = (unsigned long long*)(ws + shorts_main);

    zero_kernel<<<dim3((out_size / 4 + 255) / 256), 256, 0, stream>>>(out, out_size);
    maskpack_kernel<<<dim3(NN * (NN / 64) / 4), 256, 0, stream>>>(mask, mb);
    proj_kernel<<<dim3(32, 16, 3), 256, 0, stream>>>(q, k, v, Qw, Kw, Vw, ws);
    attn_kernel<<<dim3(32, 16), 256, 0, stream>>>(ws, mb);
    final2_kernel<<<dim3(32, 4, 4), 256, 0, stream>>>(ws + (size_t)3 * HN * NN * DD, last, out);
}

// Round 8
// 165.232 us; speedup vs baseline: 1.4585x; 1.4585x over previous
//
#include <hip/hip_runtime.h>
#include <hip/hip_bf16.h>

// MultiHeadAttention: N=2048, H=16, D=128. f32 in, f32 out, int32 mask.
// R12: R11's no-LDS attn regressed 61->137us (MfmaUtil 9.9%: per-frag
// 32-row-gather global reads swamp the memory pipe; LDS staging's real role
// was COALESCING, same mechanism as R10's proj2 regression). -> attn
// REVERTED to R9 (60us, 0 conflicts). proj attacked within the proven
// coalesced-stage pattern instead:
//   wprep (R10, proven): W -> bf16 W^T global, once (48 blocks).
//   proj3: stage W^T -> LDS via 8 coalesced b128 writes (no transpose, no
//   f2bf, vs R9's 64 8-way-conflicted ds_write_b16), frag reads = single
//   conflict-free ds_read_b128 (pitch 136), 128 tokens/block (staging
//   amortized 2x; grid 16x16x3 = 768).
// zero/maskpack/final2 unchanged from R9.

#define HN 16
#define NN 2048
#define DD 128

typedef __attribute__((ext_vector_type(8))) short short8;    // MFMA A/B frag
typedef __attribute__((ext_vector_type(4))) short short4v;
typedef __attribute__((ext_vector_type(4))) float float4v;   // 16x16 C/D frag
typedef __attribute__((ext_vector_type(16))) float f32x16;   // 32x32 C/D frag
typedef __attribute__((ext_vector_type(4))) unsigned int uint4v;

#define CROW(r) ((((r) & 3)) + 8 * ((r) >> 2))   // 32x32 C/D row for reg r

__device__ inline unsigned short f2bf(float f) {
    unsigned int u = __builtin_bit_cast(unsigned int, f);
    unsigned int r = (u + 0x7fffu + ((u >> 16) & 1u)) >> 16;  // RNE
    return (unsigned short)r;
}

// packed f32x2 -> bf16x2 (RNE), gfx950 v_cvt_pk_bf16_f32
__device__ inline unsigned int cvtpk(float lo, float hi) {
    unsigned int w;
    asm("v_cvt_pk_bf16_f32 %0, %1, %2" : "=v"(w) : "v"(lo), "v"(hi));
    return w;
}

// exchange lane-halves: x' = {lo: x, hi: y from lane-32};
//                       y' = {lo: x from lane+32, hi: y}
__device__ inline void plswap(unsigned int& x, unsigned int& y) {
#if __has_builtin(__builtin_amdgcn_permlane32_swap)
    typedef int int2v __attribute__((ext_vector_type(2)));
    int2v r = __builtin_amdgcn_permlane32_swap((int)x, (int)y, false, false);
    x = (unsigned int)r[0];
    y = (unsigned int)r[1];
#else
    const unsigned int sx = (unsigned int)__shfl_xor((int)x, 32);
    const unsigned int sy = (unsigned int)__shfl_xor((int)y, 32);
    const bool hiHalf = (threadIdx.x & 32) != 0;
    const unsigned int nx = hiHalf ? sy : x;
    const unsigned int ny = hiHalf ? y : sx;
    x = nx; y = ny;
#endif
}

// 8 contiguous f32 -> bf16 MFMA frag
__device__ inline short8 ld_bf8(const float* __restrict__ p) {
    const float4v a = *(const float4v*)p;
    const float4v b = *(const float4v*)(p + 4);
    short8 r;
    r[0] = (short)f2bf(a[0]); r[1] = (short)f2bf(a[1]);
    r[2] = (short)f2bf(a[2]); r[3] = (short)f2bf(a[3]);
    r[4] = (short)f2bf(b[0]); r[5] = (short)f2bf(b[1]);
    r[6] = (short)f2bf(b[2]); r[7] = (short)f2bf(b[3]);
    return r;
}

// two ds_read_b64 frag load (for odd-pitch LDS arrays; needs 8B align)
__device__ inline short8 ld2x4(const unsigned short* p) {
    const short4v lo = *(const short4v*)p;
    const short4v hi = *(const short4v*)(p + 4);
    short8 r;
    r[0] = lo[0]; r[1] = lo[1]; r[2] = lo[2]; r[3] = lo[3];
    r[4] = hi[0]; r[5] = hi[1]; r[6] = hi[2]; r[7] = hi[3];
    return r;
}

__global__ void sentinel_kernel(float* out, int n) {
    int i = blockIdx.x * 256 + threadIdx.x;
    if (i < n) out[i] = 2.0f;
}

__global__ __launch_bounds__(256) void zero_kernel(float* __restrict__ out, int n) {
    const int i4 = blockIdx.x * 256 + threadIdx.x;
    if (i4 * 4 + 3 < n) {
        *(float4v*)(out + i4 * 4) = float4v{0.f, 0.f, 0.f, 0.f};
    } else {
        for (int i = i4 * 4; i < n; i++) out[i] = 0.f;
    }
}

// ---------------------------------------------------------------------------
// Kernel M: pack mask[2048][2048] int32 into bits.
// ---------------------------------------------------------------------------
__global__ __launch_bounds__(256) void maskpack_kernel(
    const int* __restrict__ mask,
    unsigned long long* __restrict__ mb)
{
    const int word = blockIdx.x * 4 + (threadIdx.x >> 6);
    const int lane = threadIdx.x & 63;
    const int i = word >> 5;   // row
    const int w = word & 31;   // 64-col word within row
    const int mv = mask[(size_t)i * NN + w * 64 + lane];
    const unsigned long long b = __ballot(mv != 0);
    if (lane == 0) mb[word] = b;
}

// ---------------------------------------------------------------------------
// Kernel W: one-shot W transpose+convert. grid = (16 heads, 3 tensors).
// wsW[t][h][e][d] = bf16(W[t][h][d][e]). (proven in R10)
// ---------------------------------------------------------------------------
__global__ __launch_bounds__(256) void wprep_kernel(
    const float* __restrict__ Qw,
    const float* __restrict__ Kw,
    const float* __restrict__ Vw,
    unsigned short* __restrict__ wsW)
{
    __shared__ __align__(16) unsigned short Wt[128 * 132];
    const int h = blockIdx.x, t = blockIdx.y;
    const float* W = ((t == 0) ? Qw : ((t == 1) ? Kw : Vw)) + h * DD * DD;
    unsigned short* o = wsW + ((size_t)t * HN + h) * DD * DD;
    const int tid = threadIdx.x;

    for (int idx2 = tid * 2; idx2 < DD * DD; idx2 += 512) {
        const int d = idx2 >> 7, e = idx2 & 127;
        const float2 w2 = *(const float2*)(W + idx2);
        Wt[(e + 0) * 132 + d] = f2bf(w2.x);
        Wt[(e + 1) * 132 + d] = f2bf(w2.y);
    }
    __syncthreads();
    for (int idx8 = tid * 8; idx8 < DD * DD; idx8 += 2048) {
        const int e = idx8 >> 7, d = idx8 & 127;
        *(short8*)(o + idx8) = ld2x4(&Wt[e * 132 + d]);
    }
}

// ---------------------------------------------------------------------------
// Kernel A: projections v3. grid = (16 token-chunks, 16 heads, 3 tensors).
// Stage bf16 W^T -> LDS (8 coalesced b128 writes/thread, pitch 136), then
// 2 x 64-token tiles: frag reads are single conflict-free ds_read_b128
// ((68*l16)%32 -> 2-way = free). t<2: out[n][d]; t==2: vpT via operand swap.
// ---------------------------------------------------------------------------
__global__ __launch_bounds__(256) void proj3_kernel(
    const float* __restrict__ q,
    const float* __restrict__ k,
    const float* __restrict__ v,
    const unsigned short* __restrict__ wsW,
    unsigned short* __restrict__ ws)
{
    __shared__ __align__(16) unsigned short Wt[128 * 136];  // [e][d], pitch 136
    const int t = blockIdx.z, h = blockIdx.y, cb = blockIdx.x;
    const int tid = threadIdx.x;
    const float* in = (t == 0) ? q : ((t == 1) ? k : v);
    const unsigned short* WTg = wsW + ((size_t)t * HN + h) * DD * DD;
    unsigned short* out = ws + (size_t)t * (HN * NN * DD) + (size_t)h * (NN * DD);

#pragma unroll
    for (int it = 0; it < 8; it++) {
        const int idx8 = tid * 8 + it * 2048;
        const int row = idx8 >> 7, col = idx8 & 127;
        *(short8*)(&Wt[row * 136 + col]) = *(const short8*)(WTg + idx8);
    }
    __syncthreads();

    const int wave = tid >> 6, lane = tid & 63;
    const int quad = lane >> 4, l16 = lane & 15;

#pragma unroll 1
    for (int rt = 0; rt < 2; rt++) {
        const int row0 = cb * 128 + rt * 64 + wave * 16;

        float4v acc[8];
#pragma unroll
        for (int c = 0; c < 8; c++) acc[c] = {0.f, 0.f, 0.f, 0.f};

        if (t < 2) {
            // D[token][e]: A = input rows, B = Wt rows
#pragma unroll
            for (int kk = 0; kk < 4; kk++) {
                const short8 a = ld_bf8(in + (size_t)(row0 + l16) * DD + kk * 32 + quad * 8);
#pragma unroll
                for (int c = 0; c < 8; c++) {
                    const short8 b = *(const short8*)(&Wt[(c * 16 + l16) * 136 + kk * 32 + quad * 8]);
                    acc[c] = __builtin_amdgcn_mfma_f32_16x16x32_bf16(a, b, acc[c], 0, 0, 0);
                }
            }
#pragma unroll
            for (int c = 0; c < 8; c++)
#pragma unroll
                for (int r = 0; r < 4; r++)
                    out[(size_t)(row0 + quad * 4 + r) * DD + c * 16 + l16] = f2bf(acc[c][r]);
        } else {
            // D[e][token] = vpT: A = Wt rows (Wv^T), B = v rows; swapped
#pragma unroll
            for (int kk = 0; kk < 4; kk++) {
                const short8 bv = ld_bf8(in + (size_t)(row0 + l16) * DD + kk * 32 + quad * 8);
#pragma unroll
                for (int c = 0; c < 8; c++) {
                    const short8 aw = *(const short8*)(&Wt[(c * 16 + l16) * 136 + kk * 32 + quad * 8]);
                    acc[c] = __builtin_amdgcn_mfma_f32_16x16x32_bf16(aw, bv, acc[c], 0, 0, 0);
                }
            }
#pragma unroll
            for (int c = 0; c < 8; c++)
#pragma unroll
                for (int r = 0; r < 4; r++)
                    out[(size_t)(c * 16 + quad * 4 + r) * NN + row0 + l16] = f2bf(acc[c][r]);
        }
    }
}

// ---------------------------------------------------------------------------
// Kernel B: flash attention (R9 version, proven 60us / 0 conflicts).
// grid = (32 i-tiles, 16 heads), 4 waves: wave = (ig = i-half, h2 = j-half).
// Double-buffered LDS staging (coalesced), P in regs (T12), 32x32x16 MFMA.
// ---------------------------------------------------------------------------
__global__ __launch_bounds__(256, 2) void attn_kernel(
    unsigned short* __restrict__ ws,
    const unsigned long long* __restrict__ mb)
{
    __shared__ __align__(16) unsigned short qs[2][64 * 136];     // qp j-tile row-major
    __shared__ __align__(16) unsigned short vpTile[2][128 * 72]; // vpT j-tile [d][j]

    const int h = blockIdx.y, ib = blockIdx.x;
    const int tid = threadIdx.x;
    const int wave = tid >> 6, lane = tid & 63;
    const int ig = wave >> 1;        // i-group: 0 -> rows 0..31, 1 -> 32..63
    const int h2 = wave & 1;         // j-half of the 64-j tile
    const int l31 = lane & 31;
    const int hi = lane >> 5;        // lane half

    const unsigned short* qp  = ws + (size_t)h * (NN * DD);
    const unsigned short* kp  = ws + (size_t)(HN * NN * DD) + (size_t)h * (NN * DD);
    const unsigned short* vpT = ws + (size_t)(2 * HN * NN * DD) + (size_t)h * (NN * DD);
    unsigned short* ao = ws + (size_t)(3 * HN * NN * DD);  // [N][H*D]

    const int i0 = ib * 64;
    const float scale = 0.022097086912079612f;  // 1/sqrt(2048)

    // kp B-frags (B[k=d][n=i], lane&31 = i): loaded once, reused all iters.
    short8 kpf[8];
    {
        const int row = i0 + ig * 32 + l31;
#pragma unroll
        for (int kk = 0; kk < 8; kk++)
            kpf[kk] = *(const short8*)(kp + (size_t)row * DD + kk * 16 + hi * 8);
    }

    // register staging buffers for the next tile (4x qp chunks, 4x vpT chunks)
    short8 rq[4], rv[4];

#define LOADT(J0) do {                                                         \
        _Pragma("unroll")                                                      \
        for (int it = 0; it < 4; it++) {                                       \
            const int idx = tid * 8 + it * 2048;                               \
            rq[it] = *(const short8*)(qp + (size_t)(J0) * DD + idx);           \
            rv[it] = *(const short8*)(vpT + (size_t)(idx >> 6) * NN + (J0) + (idx & 63)); \
        } } while (0)

#define WRITET(BUF) do {                                                       \
        _Pragma("unroll")                                                      \
        for (int it = 0; it < 4; it++) {                                       \
            const int idx = tid * 8 + it * 2048;                               \
            *(short8*)(&qs[BUF][(idx >> 7) * 136 + (idx & 127)]) = rq[it];     \
            *(short8*)(&vpTile[BUF][(idx >> 6) * 72 + (idx & 63)]) = rv[it];   \
        } } while (0)

    f32x16 o[4];
#pragma unroll
    for (int dt = 0; dt < 4; dt++)
#pragma unroll
        for (int r = 0; r < 16; r++) o[dt][r] = 0.f;
    float lacc = 0.f;

    // Per-iteration compute on buffer `buf`, mask word column `jt`.
    // T[j][i] = sum_d qp[j][d]*kp[i][d]: A = qp rows (LDS), B = kp (regs).
    // C/D: col = lane&31 = i, row j = CROW(r) + 4*hi (+ h2*32 in tile).
    auto COMPUTE = [&](int buf, int jt) {
        const unsigned long long mrow = mb[(size_t)(i0 + ig * 32 + l31) * 32 + jt];
        const unsigned int m2 = (unsigned int)(mrow >> (h2 * 32 + hi * 4));

        f32x16 s;
#pragma unroll
        for (int r = 0; r < 16; r++) s[r] = 0.f;
#pragma unroll
        for (int kk = 0; kk < 8; kk++) {
            const short8 aq = *(const short8*)(&qs[buf][(h2 * 32 + l31) * 136 + kk * 16 + hi * 8]);
            s = __builtin_amdgcn_mfma_f32_32x32x16_bf16(aq, kpf[kk], s, 0, 0, 0);
        }

        // static-max softmax: p = exp(s*scale - 5) (masked -> exp(-50) ~ 0)
#pragma unroll
        for (int r = 0; r < 16; r++) {
            const float x = ((m2 >> CROW(r)) & 1u) ? fmaf(s[r], scale, -5.0f) : -50.0f;
            s[r] = __expf(x);
        }
        // row-sum over this j-tile for denominator (i = lane&31)
        float ls = (((s[0] + s[1]) + (s[2] + s[3])) + ((s[4] + s[5]) + (s[6] + s[7])))
                 + (((s[8] + s[9]) + (s[10] + s[11])) + ((s[12] + s[13]) + (s[14] + s[15])));
        ls += __shfl_xor(ls, 32);
        lacc += ls;

        // T12 repack: P -> two PV A-frags (lane = i, k = j), zero LDS.
        short8 pa[2];
#pragma unroll
        for (int ks = 0; ks < 2; ks++) {
            const int b = ks * 8;
            unsigned int x0 = cvtpk(s[b + 0], s[b + 1]);
            unsigned int y0 = cvtpk(s[b + 4], s[b + 5]);
            unsigned int x1 = cvtpk(s[b + 2], s[b + 3]);
            unsigned int y1 = cvtpk(s[b + 6], s[b + 7]);
            plswap(x0, y0);   // x0 -> e0e1 (lo j0j1 / hi j8j9), y0 -> e4e5
            plswap(x1, y1);   // x1 -> e2e3, y1 -> e6e7
            uint4v w; w[0] = x0; w[1] = x1; w[2] = y0; w[3] = y1;
            pa[ks] = __builtin_bit_cast(short8, w);
        }

        // O[i][d] += P · vp  (B from vpT tile: lane&31 = d, k = j chunk)
#pragma unroll
        for (int ks = 0; ks < 2; ks++) {
#pragma unroll
            for (int dt = 0; dt < 4; dt++) {
                const short8 bv = *(const short8*)(&vpTile[buf][(dt * 32 + l31) * 72 + h2 * 32 + ks * 16 + hi * 8]);
                o[dt] = __builtin_amdgcn_mfma_f32_32x32x16_bf16(pa[ks], bv, o[dt], 0, 0, 0);
            }
        }
    };

    // Prologue: tile 0 -> LDS[0]; tile 1 in flight in regs.
    LOADT(0);
    WRITET(0);
    LOADT(64);
    __syncthreads();

    int cur = 0;

#pragma unroll 1
    for (int jt = 0; jt < 30; ++jt) {
        WRITET(cur ^ 1);
        LOADT((jt + 2) * 64);
        COMPUTE(cur, jt);
        __syncthreads();
        cur ^= 1;
    }
    WRITET(cur ^ 1);
    COMPUTE(cur, 30);
    __syncthreads();
    cur ^= 1;
    COMPUTE(cur, 31);

#undef LOADT
#undef WRITET

    // Epilogue: combine partner-wave partials (same ig, other j-half) via the
    // now-dead LDS, normalize, store.
    __syncthreads();                          // all waves done with qs/vpTile
    float* obuf = (float*)&qs[0][0];          // 32 KB needed, 34 KB available
    float* lbuf = (float*)&vpTile[0][0];      // 128 f32 used

    if (h2 == 1) {
#pragma unroll
        for (int dt = 0; dt < 4; dt++)
#pragma unroll
            for (int r = 0; r < 16; r++)
                obuf[(((ig * 2 + hi) * 4 + dt) * 16 + r) * 32 + l31] = o[dt][r];
        if (hi == 0) lbuf[ig * 32 + l31] = lacc;
    }
    __syncthreads();
    if (h2 == 0) {
        const float lt = lacc + lbuf[ig * 32 + l31];
        const float inv = (lt > 0.f) ? (1.0f / lt) : 0.f;
        if (hi == 0) lbuf[64 + ig * 32 + l31] = inv;  // same-wave RAW, lgkm-ordered
#pragma unroll
        for (int dt = 0; dt < 4; dt++)
#pragma unroll
            for (int r = 0; r < 16; r++) {
                const int row = CROW(r) + hi * 4;     // i_local 0..31
                const float val = (o[dt][r] + obuf[(((ig * 2 + hi) * 4 + dt) * 16 + r) * 32 + l31])
                                  * lbuf[64 + ig * 32 + row];
                ao[(size_t)(i0 + ig * 32 + row) * (HN * DD) + h * DD + dt * 32 + l31] = f2bf(val);
            }
    }
}

// ---------------------------------------------------------------------------
// Kernel C: final GEMM [2048,2048]x[2048,128] -> f32, K-split x4.
// grid = (32 i, 4 e, 4 ks) = 512 blocks (2/CU). Whole 512-K `last` slice
// staged once; ONE barrier; 8 unrolled barrier-free MFMA iters; atomicAdd.
// ---------------------------------------------------------------------------
__global__ __launch_bounds__(256) void final2_kernel(
    const unsigned short* __restrict__ ao,
    const float* __restrict__ last,
    float* __restrict__ outp)
{
    __shared__ __align__(16) unsigned short lt[32 * 516];  // [e_local][k_local]
    const int tid = threadIdx.x;
    const int wave = tid >> 6, lane = tid & 63;
    const int quad = lane >> 4, l16 = lane & 15;
    const int i0 = blockIdx.x * 64;
    const int e0 = blockIdx.y * 32;
    const int k0 = blockIdx.z * 512;

    // stage last[k0..+512][e0..+32] transposed -> lt[e][k] bf16
#pragma unroll
    for (int idx2 = tid * 2; idx2 < 512 * 32; idx2 += 512) {
        const int kk = idx2 >> 5, e = idx2 & 31;
        const float2 w2 = *(const float2*)(last + (size_t)(k0 + kk) * DD + e0 + e);
        lt[(e + 0) * 516 + kk] = f2bf(w2.x);
        lt[(e + 1) * 516 + kk] = f2bf(w2.y);
    }
    __syncthreads();

    float4v acc[2];
    acc[0] = {0.f, 0.f, 0.f, 0.f};
    acc[1] = {0.f, 0.f, 0.f, 0.f};

    const unsigned short* arow = ao + (size_t)(i0 + wave * 16 + l16) * (HN * DD) + k0;

#pragma unroll
    for (int kb = 0; kb < 8; kb++) {
#pragma unroll
        for (int ks = 0; ks < 2; ks++) {
            const short8 a = *(const short8*)(arow + kb * 64 + ks * 32 + quad * 8);
#pragma unroll
            for (int dc = 0; dc < 2; dc++) {
                const short8 b = ld2x4(&lt[(dc * 16 + l16) * 516 + kb * 64 + ks * 32 + quad * 8]);
                acc[dc] = __builtin_amdgcn_mfma_f32_16x16x32_bf16(a, b, acc[dc], 0, 0, 0);
            }
        }
    }

#pragma unroll
    for (int r = 0; r < 4; r++)
#pragma unroll
        for (int dc = 0; dc < 2; dc++)
            atomicAdd(&outp[(size_t)(i0 + wave * 16 + quad * 4 + r) * DD + e0 + dc * 16 + l16],
                      acc[dc][r]);
}

extern "C" void kernel_launch(void* const* d_in, const int* in_sizes, int n_in,
                              void* d_out, int out_size, void* d_ws, size_t ws_size,
                              hipStream_t stream)
{
    const float* q    = (const float*)d_in[0];
    const float* k    = (const float*)d_in[1];
    const float* v    = (const float*)d_in[2];
    const int*   mask = (const int*)d_in[3];
    const float* Qw   = (const float*)d_in[4];
    const float* Kw   = (const float*)d_in[5];
    const float* Vw   = (const float*)d_in[6];
    const float* last = (const float*)d_in[7];
    unsigned short* ws  = (unsigned short*)d_ws;
    float* out = (float*)d_out;

    // ws (bf16): qp[16*2048*128] | kp[...] | vpT[16][128][2048] | ao[2048][2048]
    //            | mb[2048][32] u64 (bitpacked mask)
    // wsW (bf16 W^T, 1.5MB) lives INSIDE the ao region (dead until attn).
    const size_t shorts_main = (size_t)4 * HN * NN * DD;   // qp+kp+vpT+ao
    const size_t mb_bytes = (size_t)NN * (NN / 64) * 8;
    const size_t needed = shorts_main * sizeof(unsigned short) + mb_bytes;
    if (ws_size < needed) {
        sentinel_kernel<<<(out_size + 255) / 256, 256, 0, stream>>>(out, out_size);
        return;
    }
    unsigned long long* mb = (unsigned long long*)(ws + shorts_main);
    unsigned short* wsW = ws + (size_t)3 * HN * NN * DD;   // = ao region

    zero_kernel<<<dim3((out_size / 4 + 255) / 256), 256, 0, stream>>>(out, out_size);
    maskpack_kernel<<<dim3(NN * (NN / 64) / 4), 256, 0, stream>>>(mask, mb);
    wprep_kernel<<<dim3(16, 3), 256, 0, stream>>>(Qw, Kw, Vw, wsW);
    proj3_kernel<<<dim3(16, 16, 3), 256, 0, stream>>>(q, k, v, wsW, ws);
    attn_kernel<<<dim3(32, 16), 256, 0, stream>>>(ws, mb);
    final2_kernel<<<dim3(32, 4, 4), 256, 0, stream>>>(ws + (size_t)3 * HN * NN * DD, last, out);
}

// Round 9
// 161.636 us; speedup vs baseline: 1.4910x; 1.0222x over previous
//
#include <hip/hip_runtime.h>
#include <hip/hip_bf16.h>

// MultiHeadAttention: N=2048, H=16, D=128. f32 in, f32 out, int32 mask.
// R13 (low-risk bundle on R12 base, 165.2us):
//  (1) attn: T5 s_setprio(1/0) around QK and PV MFMA clusters (2 blocks/CU
//      at different phases -> scheduler favors MFMA waves; guide: +4-7%).
//  (2) attn: light main-loop barrier (lgkmcnt(0) + sched_barrier +
//      s_barrier) instead of __syncthreads' vmcnt(0) drain -> LOADT
//      prefetch spans barriers (T4-lite). Correctness: barrier only needs
//      LDS ordering; rq/rv consumption is vmcnt-guarded by compiler.
//  (3) maskpack2: 4 words/wave (4 coalesced 256B loads + 4 ballots),
//      grid 4096; out-zeroing fused in; zero_kernel launch deleted.
// wprep/proj3/attn-structure/final2 unchanged from R12.

#define HN 16
#define NN 2048
#define DD 128

typedef __attribute__((ext_vector_type(8))) short short8;    // MFMA A/B frag
typedef __attribute__((ext_vector_type(4))) short short4v;
typedef __attribute__((ext_vector_type(4))) float float4v;   // 16x16 C/D frag
typedef __attribute__((ext_vector_type(16))) float f32x16;   // 32x32 C/D frag
typedef __attribute__((ext_vector_type(4))) unsigned int uint4v;

#define CROW(r) ((((r) & 3)) + 8 * ((r) >> 2))   // 32x32 C/D row for reg r

__device__ inline unsigned short f2bf(float f) {
    unsigned int u = __builtin_bit_cast(unsigned int, f);
    unsigned int r = (u + 0x7fffu + ((u >> 16) & 1u)) >> 16;  // RNE
    return (unsigned short)r;
}

// packed f32x2 -> bf16x2 (RNE), gfx950 v_cvt_pk_bf16_f32
__device__ inline unsigned int cvtpk(float lo, float hi) {
    unsigned int w;
    asm("v_cvt_pk_bf16_f32 %0, %1, %2" : "=v"(w) : "v"(lo), "v"(hi));
    return w;
}

// exchange lane-halves: x' = {lo: x, hi: y from lane-32};
//                       y' = {lo: x from lane+32, hi: y}
__device__ inline void plswap(unsigned int& x, unsigned int& y) {
#if __has_builtin(__builtin_amdgcn_permlane32_swap)
    typedef int int2v __attribute__((ext_vector_type(2)));
    int2v r = __builtin_amdgcn_permlane32_swap((int)x, (int)y, false, false);
    x = (unsigned int)r[0];
    y = (unsigned int)r[1];
#else
    const unsigned int sx = (unsigned int)__shfl_xor((int)x, 32);
    const unsigned int sy = (unsigned int)__shfl_xor((int)y, 32);
    const bool hiHalf = (threadIdx.x & 32) != 0;
    const unsigned int nx = hiHalf ? sy : x;
    const unsigned int ny = hiHalf ? y : sx;
    x = nx; y = ny;
#endif
}

// LDS-only barrier: drain this wave's LDS ops, then raw s_barrier.
// (No vmcnt(0) drain -> global prefetch loads stay in flight across it.)
__device__ inline void bar_lds() {
    asm volatile("s_waitcnt lgkmcnt(0)" ::: "memory");
    __builtin_amdgcn_sched_barrier(0);
    __builtin_amdgcn_s_barrier();
    __builtin_amdgcn_sched_barrier(0);
}

// 8 contiguous f32 -> bf16 MFMA frag
__device__ inline short8 ld_bf8(const float* __restrict__ p) {
    const float4v a = *(const float4v*)p;
    const float4v b = *(const float4v*)(p + 4);
    short8 r;
    r[0] = (short)f2bf(a[0]); r[1] = (short)f2bf(a[1]);
    r[2] = (short)f2bf(a[2]); r[3] = (short)f2bf(a[3]);
    r[4] = (short)f2bf(b[0]); r[5] = (short)f2bf(b[1]);
    r[6] = (short)f2bf(b[2]); r[7] = (short)f2bf(b[3]);
    return r;
}

// two ds_read_b64 frag load (for odd-pitch LDS arrays; needs 8B align)
__device__ inline short8 ld2x4(const unsigned short* p) {
    const short4v lo = *(const short4v*)p;
    const short4v hi = *(const short4v*)(p + 4);
    short8 r;
    r[0] = lo[0]; r[1] = lo[1]; r[2] = lo[2]; r[3] = lo[3];
    r[4] = hi[0]; r[5] = hi[1]; r[6] = hi[2]; r[7] = hi[3];
    return r;
}

__global__ void sentinel_kernel(float* out, int n) {
    int i = blockIdx.x * 256 + threadIdx.x;
    if (i < n) out[i] = 2.0f;
}

// ---------------------------------------------------------------------------
// Kernel M2: pack mask into bits, 4 words/wave, + fused out-zeroing.
// grid 4096 x 256. wgrp = 4-word group; 4 coalesced 256B loads + 4 ballots.
// ---------------------------------------------------------------------------
__global__ __launch_bounds__(256) void maskpack2_kernel(
    const int* __restrict__ mask,
    unsigned long long* __restrict__ mb,
    float* __restrict__ out, int out_n)
{
    const int wgrp = blockIdx.x * 4 + (threadIdx.x >> 6);  // 0..16383
    const int lane = threadIdx.x & 63;
    const int word0 = wgrp * 4;          // 4 consecutive words, same row
    const int i = word0 >> 5;            // row
    const int w = word0 & 31;            // word within row
    const int* row = mask + (size_t)i * NN + w * 64;
    unsigned long long b[4];
#pragma unroll
    for (int c = 0; c < 4; c++)
        b[c] = __ballot(row[c * 64 + lane] != 0);
    if (lane == 0) {
#pragma unroll
        for (int c = 0; c < 4; c++) mb[word0 + c] = b[c];
    }
    // fused zero of out (for final2's atomicAdd)
    const int z = blockIdx.x * 256 + threadIdx.x;
    if (z < out_n) out[z] = 0.f;
}

// ---------------------------------------------------------------------------
// Kernel W: one-shot W transpose+convert. grid = (16 heads, 3 tensors).
// wsW[t][h][e][d] = bf16(W[t][h][d][e]).
// ---------------------------------------------------------------------------
__global__ __launch_bounds__(256) void wprep_kernel(
    const float* __restrict__ Qw,
    const float* __restrict__ Kw,
    const float* __restrict__ Vw,
    unsigned short* __restrict__ wsW)
{
    __shared__ __align__(16) unsigned short Wt[128 * 132];
    const int h = blockIdx.x, t = blockIdx.y;
    const float* W = ((t == 0) ? Qw : ((t == 1) ? Kw : Vw)) + h * DD * DD;
    unsigned short* o = wsW + ((size_t)t * HN + h) * DD * DD;
    const int tid = threadIdx.x;

    for (int idx2 = tid * 2; idx2 < DD * DD; idx2 += 512) {
        const int d = idx2 >> 7, e = idx2 & 127;
        const float2 w2 = *(const float2*)(W + idx2);
        Wt[(e + 0) * 132 + d] = f2bf(w2.x);
        Wt[(e + 1) * 132 + d] = f2bf(w2.y);
    }
    __syncthreads();
    for (int idx8 = tid * 8; idx8 < DD * DD; idx8 += 2048) {
        const int e = idx8 >> 7, d = idx8 & 127;
        *(short8*)(o + idx8) = ld2x4(&Wt[e * 132 + d]);
    }
}

// ---------------------------------------------------------------------------
// Kernel A: projections v3. grid = (16 token-chunks, 16 heads, 3 tensors).
// Stage bf16 W^T -> LDS (coalesced b128), frag reads conflict-free b128.
// ---------------------------------------------------------------------------
__global__ __launch_bounds__(256) void proj3_kernel(
    const float* __restrict__ q,
    const float* __restrict__ k,
    const float* __restrict__ v,
    const unsigned short* __restrict__ wsW,
    unsigned short* __restrict__ ws)
{
    __shared__ __align__(16) unsigned short Wt[128 * 136];  // [e][d], pitch 136
    const int t = blockIdx.z, h = blockIdx.y, cb = blockIdx.x;
    const int tid = threadIdx.x;
    const float* in = (t == 0) ? q : ((t == 1) ? k : v);
    const unsigned short* WTg = wsW + ((size_t)t * HN + h) * DD * DD;
    unsigned short* out = ws + (size_t)t * (HN * NN * DD) + (size_t)h * (NN * DD);

#pragma unroll
    for (int it = 0; it < 8; it++) {
        const int idx8 = tid * 8 + it * 2048;
        const int row = idx8 >> 7, col = idx8 & 127;
        *(short8*)(&Wt[row * 136 + col]) = *(const short8*)(WTg + idx8);
    }
    __syncthreads();

    const int wave = tid >> 6, lane = tid & 63;
    const int quad = lane >> 4, l16 = lane & 15;

#pragma unroll 1
    for (int rt = 0; rt < 2; rt++) {
        const int row0 = cb * 128 + rt * 64 + wave * 16;

        float4v acc[8];
#pragma unroll
        for (int c = 0; c < 8; c++) acc[c] = {0.f, 0.f, 0.f, 0.f};

        if (t < 2) {
#pragma unroll
            for (int kk = 0; kk < 4; kk++) {
                const short8 a = ld_bf8(in + (size_t)(row0 + l16) * DD + kk * 32 + quad * 8);
#pragma unroll
                for (int c = 0; c < 8; c++) {
                    const short8 b = *(const short8*)(&Wt[(c * 16 + l16) * 136 + kk * 32 + quad * 8]);
                    acc[c] = __builtin_amdgcn_mfma_f32_16x16x32_bf16(a, b, acc[c], 0, 0, 0);
                }
            }
#pragma unroll
            for (int c = 0; c < 8; c++)
#pragma unroll
                for (int r = 0; r < 4; r++)
                    out[(size_t)(row0 + quad * 4 + r) * DD + c * 16 + l16] = f2bf(acc[c][r]);
        } else {
#pragma unroll
            for (int kk = 0; kk < 4; kk++) {
                const short8 bv = ld_bf8(in + (size_t)(row0 + l16) * DD + kk * 32 + quad * 8);
#pragma unroll
                for (int c = 0; c < 8; c++) {
                    const short8 aw = *(const short8*)(&Wt[(c * 16 + l16) * 136 + kk * 32 + quad * 8]);
                    acc[c] = __builtin_amdgcn_mfma_f32_16x16x32_bf16(aw, bv, acc[c], 0, 0, 0);
                }
            }
#pragma unroll
            for (int c = 0; c < 8; c++)
#pragma unroll
                for (int r = 0; r < 4; r++)
                    out[(size_t)(c * 16 + quad * 4 + r) * NN + row0 + l16] = f2bf(acc[c][r]);
        }
    }
}

// ---------------------------------------------------------------------------
// Kernel B: flash attention (R9 structure + setprio + light barriers).
// grid = (32 i-tiles, 16 heads), 4 waves: wave = (ig = i-half, h2 = j-half).
// ---------------------------------------------------------------------------
__global__ __launch_bounds__(256, 2) void attn_kernel(
    unsigned short* __restrict__ ws,
    const unsigned long long* __restrict__ mb)
{
    __shared__ __align__(16) unsigned short qs[2][64 * 136];     // qp j-tile row-major
    __shared__ __align__(16) unsigned short vpTile[2][128 * 72]; // vpT j-tile [d][j]

    const int h = blockIdx.y, ib = blockIdx.x;
    const int tid = threadIdx.x;
    const int wave = tid >> 6, lane = tid & 63;
    const int ig = wave >> 1;        // i-group: 0 -> rows 0..31, 1 -> 32..63
    const int h2 = wave & 1;         // j-half of the 64-j tile
    const int l31 = lane & 31;
    const int hi = lane >> 5;        // lane half

    const unsigned short* qp  = ws + (size_t)h * (NN * DD);
    const unsigned short* kp  = ws + (size_t)(HN * NN * DD) + (size_t)h * (NN * DD);
    const unsigned short* vpT = ws + (size_t)(2 * HN * NN * DD) + (size_t)h * (NN * DD);
    unsigned short* ao = ws + (size_t)(3 * HN * NN * DD);  // [N][H*D]

    const int i0 = ib * 64;
    const float scale = 0.022097086912079612f;  // 1/sqrt(2048)

    // kp B-frags (B[k=d][n=i], lane&31 = i): loaded once, reused all iters.
    short8 kpf[8];
    {
        const int row = i0 + ig * 32 + l31;
#pragma unroll
        for (int kk = 0; kk < 8; kk++)
            kpf[kk] = *(const short8*)(kp + (size_t)row * DD + kk * 16 + hi * 8);
    }

    // register staging buffers for the next tile (4x qp chunks, 4x vpT chunks)
    short8 rq[4], rv[4];

#define LOADT(J0) do {                                                         \
        _Pragma("unroll")                                                      \
        for (int it = 0; it < 4; it++) {                                       \
            const int idx = tid * 8 + it * 2048;                               \
            rq[it] = *(const short8*)(qp + (size_t)(J0) * DD + idx);           \
            rv[it] = *(const short8*)(vpT + (size_t)(idx >> 6) * NN + (J0) + (idx & 63)); \
        } } while (0)

#define WRITET(BUF) do {                                                       \
        _Pragma("unroll")                                                      \
        for (int it = 0; it < 4; it++) {                                       \
            const int idx = tid * 8 + it * 2048;                               \
            *(short8*)(&qs[BUF][(idx >> 7) * 136 + (idx & 127)]) = rq[it];     \
            *(short8*)(&vpTile[BUF][(idx >> 6) * 72 + (idx & 63)]) = rv[it];   \
        } } while (0)

    f32x16 o[4];
#pragma unroll
    for (int dt = 0; dt < 4; dt++)
#pragma unroll
        for (int r = 0; r < 16; r++) o[dt][r] = 0.f;
    float lacc = 0.f;

    // Per-iteration compute on buffer `buf`, mask word column `jt`.
    // T[j][i] = sum_d qp[j][d]*kp[i][d]: A = qp rows (LDS), B = kp (regs).
    // C/D: col = lane&31 = i, row j = CROW(r) + 4*hi (+ h2*32 in tile).
    auto COMPUTE = [&](int buf, int jt) {
        const unsigned long long mrow = mb[(size_t)(i0 + ig * 32 + l31) * 32 + jt];
        const unsigned int m2 = (unsigned int)(mrow >> (h2 * 32 + hi * 4));

        f32x16 s;
#pragma unroll
        for (int r = 0; r < 16; r++) s[r] = 0.f;
        __builtin_amdgcn_s_setprio(1);
#pragma unroll
        for (int kk = 0; kk < 8; kk++) {
            const short8 aq = *(const short8*)(&qs[buf][(h2 * 32 + l31) * 136 + kk * 16 + hi * 8]);
            s = __builtin_amdgcn_mfma_f32_32x32x16_bf16(aq, kpf[kk], s, 0, 0, 0);
        }
        __builtin_amdgcn_s_setprio(0);

        // static-max softmax: p = exp(s*scale - 5) (masked -> exp(-50) ~ 0)
#pragma unroll
        for (int r = 0; r < 16; r++) {
            const float x = ((m2 >> CROW(r)) & 1u) ? fmaf(s[r], scale, -5.0f) : -50.0f;
            s[r] = __expf(x);
        }
        // row-sum over this j-tile for denominator (i = lane&31)
        float ls = (((s[0] + s[1]) + (s[2] + s[3])) + ((s[4] + s[5]) + (s[6] + s[7])))
                 + (((s[8] + s[9]) + (s[10] + s[11])) + ((s[12] + s[13]) + (s[14] + s[15])));
        ls += __shfl_xor(ls, 32);
        lacc += ls;

        // T12 repack: P -> two PV A-frags (lane = i, k = j), zero LDS.
        short8 pa[2];
#pragma unroll
        for (int ks = 0; ks < 2; ks++) {
            const int b = ks * 8;
            unsigned int x0 = cvtpk(s[b + 0], s[b + 1]);
            unsigned int y0 = cvtpk(s[b + 4], s[b + 5]);
            unsigned int x1 = cvtpk(s[b + 2], s[b + 3]);
            unsigned int y1 = cvtpk(s[b + 6], s[b + 7]);
            plswap(x0, y0);   // x0 -> e0e1 (lo j0j1 / hi j8j9), y0 -> e4e5
            plswap(x1, y1);   // x1 -> e2e3, y1 -> e6e7
            uint4v w; w[0] = x0; w[1] = x1; w[2] = y0; w[3] = y1;
            pa[ks] = __builtin_bit_cast(short8, w);
        }

        // O[i][d] += P · vp  (B from vpT tile: lane&31 = d, k = j chunk)
        __builtin_amdgcn_s_setprio(1);
#pragma unroll
        for (int ks = 0; ks < 2; ks++) {
#pragma unroll
            for (int dt = 0; dt < 4; dt++) {
                const short8 bv = *(const short8*)(&vpTile[buf][(dt * 32 + l31) * 72 + h2 * 32 + ks * 16 + hi * 8]);
                o[dt] = __builtin_amdgcn_mfma_f32_32x32x16_bf16(pa[ks], bv, o[dt], 0, 0, 0);
            }
        }
        __builtin_amdgcn_s_setprio(0);
    };

    // Prologue: tile 0 -> LDS[0]; tile 1 in flight in regs.
    LOADT(0);
    WRITET(0);
    LOADT(64);
    __syncthreads();

    int cur = 0;

#pragma unroll 1
    for (int jt = 0; jt < 30; ++jt) {
        WRITET(cur ^ 1);
        LOADT((jt + 2) * 64);
        COMPUTE(cur, jt);
        bar_lds();          // LDS-only barrier: prefetch loads stay in flight
        cur ^= 1;
    }
    WRITET(cur ^ 1);
    COMPUTE(cur, 30);
    bar_lds();
    cur ^= 1;
    COMPUTE(cur, 31);

#undef LOADT
#undef WRITET

    // Epilogue: combine partner-wave partials (same ig, other j-half) via the
    // now-dead LDS, normalize, store.
    __syncthreads();                          // all waves done with qs/vpTile
    float* obuf = (float*)&qs[0][0];          // 32 KB needed, 34 KB available
    float* lbuf = (float*)&vpTile[0][0];      // 128 f32 used

    if (h2 == 1) {
#pragma unroll
        for (int dt = 0; dt < 4; dt++)
#pragma unroll
            for (int r = 0; r < 16; r++)
                obuf[(((ig * 2 + hi) * 4 + dt) * 16 + r) * 32 + l31] = o[dt][r];
        if (hi == 0) lbuf[ig * 32 + l31] = lacc;
    }
    __syncthreads();
    if (h2 == 0) {
        const float lt = lacc + lbuf[ig * 32 + l31];
        const float inv = (lt > 0.f) ? (1.0f / lt) : 0.f;
        if (hi == 0) lbuf[64 + ig * 32 + l31] = inv;  // same-wave RAW, lgkm-ordered
#pragma unroll
        for (int dt = 0; dt < 4; dt++)
#pragma unroll
            for (int r = 0; r < 16; r++) {
                const int row = CROW(r) + hi * 4;     // i_local 0..31
                const float val = (o[dt][r] + obuf[(((ig * 2 + hi) * 4 + dt) * 16 + r) * 32 + l31])
                                  * lbuf[64 + ig * 32 + row];
                ao[(size_t)(i0 + ig * 32 + row) * (HN * DD) + h * DD + dt * 32 + l31] = f2bf(val);
            }
    }
}

// ---------------------------------------------------------------------------
// Kernel C: final GEMM [2048,2048]x[2048,128] -> f32, K-split x4.
// grid = (32 i, 4 e, 4 ks) = 512 blocks (2/CU). Whole 512-K `last` slice
// staged once; ONE barrier; 8 unrolled barrier-free MFMA iters; atomicAdd.
// ---------------------------------------------------------------------------
__global__ __launch_bounds__(256) void final2_kernel(
    const unsigned short* __restrict__ ao,
    const float* __restrict__ last,
    float* __restrict__ outp)
{
    __shared__ __align__(16) unsigned short lt[32 * 516];  // [e_local][k_local]
    const int tid = threadIdx.x;
    const int wave = tid >> 6, lane = tid & 63;
    const int quad = lane >> 4, l16 = lane & 15;
    const int i0 = blockIdx.x * 64;
    const int e0 = blockIdx.y * 32;
    const int k0 = blockIdx.z * 512;

    // stage last[k0..+512][e0..+32] transposed -> lt[e][k] bf16
#pragma unroll
    for (int idx2 = tid * 2; idx2 < 512 * 32; idx2 += 512) {
        const int kk = idx2 >> 5, e = idx2 & 31;
        const float2 w2 = *(const float2*)(last + (size_t)(k0 + kk) * DD + e0 + e);
        lt[(e + 0) * 516 + kk] = f2bf(w2.x);
        lt[(e + 1) * 516 + kk] = f2bf(w2.y);
    }
    __syncthreads();

    float4v acc[2];
    acc[0] = {0.f, 0.f, 0.f, 0.f};
    acc[1] = {0.f, 0.f, 0.f, 0.f};

    const unsigned short* arow = ao + (size_t)(i0 + wave * 16 + l16) * (HN * DD) + k0;

#pragma unroll
    for (int kb = 0; kb < 8; kb++) {
#pragma unroll
        for (int ks = 0; ks < 2; ks++) {
            const short8 a = *(const short8*)(arow + kb * 64 + ks * 32 + quad * 8);
#pragma unroll
            for (int dc = 0; dc < 2; dc++) {
                const short8 b = ld2x4(&lt[(dc * 16 + l16) * 516 + kb * 64 + ks * 32 + quad * 8]);
                acc[dc] = __builtin_amdgcn_mfma_f32_16x16x32_bf16(a, b, acc[dc], 0, 0, 0);
            }
        }
    }

#pragma unroll
    for (int r = 0; r < 4; r++)
#pragma unroll
        for (int dc = 0; dc < 2; dc++)
            atomicAdd(&outp[(size_t)(i0 + wave * 16 + quad * 4 + r) * DD + e0 + dc * 16 + l16],
                      acc[dc][r]);
}

extern "C" void kernel_launch(void* const* d_in, const int* in_sizes, int n_in,
                              void* d_out, int out_size, void* d_ws, size_t ws_size,
                              hipStream_t stream)
{
    const float* q    = (const float*)d_in[0];
    const float* k    = (const float*)d_in[1];
    const float* v    = (const float*)d_in[2];
    const int*   mask = (const int*)d_in[3];
    const float* Qw   = (const float*)d_in[4];
    const float* Kw   = (const float*)d_in[5];
    const float* Vw   = (const float*)d_in[6];
    const float* last = (const float*)d_in[7];
    unsigned short* ws  = (unsigned short*)d_ws;
    float* out = (float*)d_out;

    // ws (bf16): qp[16*2048*128] | kp[...] | vpT[16][128][2048] | ao[2048][2048]
    //            | mb[2048][32] u64 (bitpacked mask)
    // wsW (bf16 W^T, 1.5MB) lives INSIDE the ao region (dead until attn).
    const size_t shorts_main = (size_t)4 * HN * NN * DD;   // qp+kp+vpT+ao
    const size_t mb_bytes = (size_t)NN * (NN / 64) * 8;
    const size_t needed = shorts_main * sizeof(unsigned short) + mb_bytes;
    if (ws_size < needed) {
        sentinel_kernel<<<(out_size + 255) / 256, 256, 0, stream>>>(out, out_size);
        return;
    }
    unsigned long long* mb = (unsigned long long*)(ws + shorts_main);
    unsigned short* wsW = ws + (size_t)3 * HN * NN * DD;   // = ao region

    maskpack2_kernel<<<dim3(NN * (NN / 64) / 16), 256, 0, stream>>>(mask, mb, out, out_size);
    wprep_kernel<<<dim3(16, 3), 256, 0, stream>>>(Qw, Kw, Vw, wsW);
    proj3_kernel<<<dim3(16, 16, 3), 256, 0, stream>>>(q, k, v, wsW, ws);
    attn_kernel<<<dim3(32, 16), 256, 0, stream>>>(ws, mb);
    final2_kernel<<<dim3(32, 4, 4), 256, 0, stream>>>(ws + (size_t)3 * HN * NN * DD, last, out);
}

// Round 10
// 160.525 us; speedup vs baseline: 1.5013x; 1.0069x over previous
//
#include <hip/hip_runtime.h>
#include <hip/hip_bf16.h>

// MultiHeadAttention: N=2048, H=16, D=128. f32 in, f32 out, int32 mask.
// R14: attn counters pinned the wall to the LDS round-trip (24 wave-b128 =
// ~50% of 4580cyc/iter; MfmaUtil 23% == computed MFMA share exactly).
// R11 showed no-LDS fails via scattered gathers. Fix: FRAGMENT-MAJOR global
// layouts written by proj3 (free - proj3 writes with full layout freedom):
//   qA[jb][kk][32][16]  -> QK A-frag = contiguous 1KB wave-load
//   vpB[j16][d][16]     -> PV B-frag = contiguous 1KB wave-load
//   mbT[w][i]           -> mask word = coalesced 256B load (was 32x8B gather)
// attn main loop: ZERO LDS, ZERO barriers. Q reg-dbuf one tile ahead; V+mask
// issued at compute top (QK 512cyc + softmax cover L2 latency); kp loaded
// once/block (row-major, unchanged). LDS only for 33KB epilogue combine.
// maskpack2 stores transposed; wprep/final2 unchanged from R13.

#define HN 16
#define NN 2048
#define DD 128

typedef __attribute__((ext_vector_type(8))) short short8;    // MFMA A/B frag
typedef __attribute__((ext_vector_type(4))) short short4v;
typedef __attribute__((ext_vector_type(4))) float float4v;   // 16x16 C/D frag
typedef __attribute__((ext_vector_type(16))) float f32x16;   // 32x32 C/D frag
typedef __attribute__((ext_vector_type(4))) unsigned int uint4v;

#define CROW(r) ((((r) & 3)) + 8 * ((r) >> 2))   // 32x32 C/D row for reg r

__device__ inline unsigned short f2bf(float f) {
    unsigned int u = __builtin_bit_cast(unsigned int, f);
    unsigned int r = (u + 0x7fffu + ((u >> 16) & 1u)) >> 16;  // RNE
    return (unsigned short)r;
}

// packed f32x2 -> bf16x2 (RNE), gfx950 v_cvt_pk_bf16_f32
__device__ inline unsigned int cvtpk(float lo, float hi) {
    unsigned int w;
    asm("v_cvt_pk_bf16_f32 %0, %1, %2" : "=v"(w) : "v"(lo), "v"(hi));
    return w;
}

// exchange lane-halves
__device__ inline void plswap(unsigned int& x, unsigned int& y) {
#if __has_builtin(__builtin_amdgcn_permlane32_swap)
    typedef int int2v __attribute__((ext_vector_type(2)));
    int2v r = __builtin_amdgcn_permlane32_swap((int)x, (int)y, false, false);
    x = (unsigned int)r[0];
    y = (unsigned int)r[1];
#else
    const unsigned int sx = (unsigned int)__shfl_xor((int)x, 32);
    const unsigned int sy = (unsigned int)__shfl_xor((int)y, 32);
    const bool hiHalf = (threadIdx.x & 32) != 0;
    const unsigned int nx = hiHalf ? sy : x;
    const unsigned int ny = hiHalf ? y : sx;
    x = nx; y = ny;
#endif
}

// 8 contiguous f32 -> bf16 MFMA frag
__device__ inline short8 ld_bf8(const float* __restrict__ p) {
    const float4v a = *(const float4v*)p;
    const float4v b = *(const float4v*)(p + 4);
    short8 r;
    r[0] = (short)f2bf(a[0]); r[1] = (short)f2bf(a[1]);
    r[2] = (short)f2bf(a[2]); r[3] = (short)f2bf(a[3]);
    r[4] = (short)f2bf(b[0]); r[5] = (short)f2bf(b[1]);
    r[6] = (short)f2bf(b[2]); r[7] = (short)f2bf(b[3]);
    return r;
}

// two ds_read_b64 frag load (for odd-pitch LDS arrays; needs 8B align)
__device__ inline short8 ld2x4(const unsigned short* p) {
    const short4v lo = *(const short4v*)p;
    const short4v hi = *(const short4v*)(p + 4);
    short8 r;
    r[0] = lo[0]; r[1] = lo[1]; r[2] = lo[2]; r[3] = lo[3];
    r[4] = hi[0]; r[5] = hi[1]; r[6] = hi[2]; r[7] = hi[3];
    return r;
}

__global__ void sentinel_kernel(float* out, int n) {
    int i = blockIdx.x * 256 + threadIdx.x;
    if (i < n) out[i] = 2.0f;
}

// ---------------------------------------------------------------------------
// Kernel M2: pack mask into bits, TRANSPOSED: mbT[w][i] covers j = w*64+bit
// for query-row i. 4 words/wave + fused out-zeroing.
// ---------------------------------------------------------------------------
__global__ __launch_bounds__(256) void maskpack2_kernel(
    const int* __restrict__ mask,
    unsigned long long* __restrict__ mbT,
    float* __restrict__ out, int out_n)
{
    const int wgrp = blockIdx.x * 4 + (threadIdx.x >> 6);  // 0..16383
    const int lane = threadIdx.x & 63;
    const int word0 = wgrp * 4;          // 4 consecutive words, same row
    const int i = word0 >> 5;            // row
    const int w = word0 & 31;            // word within row
    const int* row = mask + (size_t)i * NN + w * 64;
    unsigned long long b[4];
#pragma unroll
    for (int c = 0; c < 4; c++)
        b[c] = __ballot(row[c * 64 + lane] != 0);
    if (lane == 0) {
#pragma unroll
        for (int c = 0; c < 4; c++) mbT[(size_t)(w + c) * NN + i] = b[c];
    }
    // fused zero of out (for final2's atomicAdd)
    const int z = blockIdx.x * 256 + threadIdx.x;
    if (z < out_n) out[z] = 0.f;
}

// ---------------------------------------------------------------------------
// Kernel W: one-shot W transpose+convert. wsW[t][h][e][d] = bf16(W[t][h][d][e]).
// ---------------------------------------------------------------------------
__global__ __launch_bounds__(256) void wprep_kernel(
    const float* __restrict__ Qw,
    const float* __restrict__ Kw,
    const float* __restrict__ Vw,
    unsigned short* __restrict__ wsW)
{
    __shared__ __align__(16) unsigned short Wt[128 * 132];
    const int h = blockIdx.x, t = blockIdx.y;
    const float* W = ((t == 0) ? Qw : ((t == 1) ? Kw : Vw)) + h * DD * DD;
    unsigned short* o = wsW + ((size_t)t * HN + h) * DD * DD;
    const int tid = threadIdx.x;

    for (int idx2 = tid * 2; idx2 < DD * DD; idx2 += 512) {
        const int d = idx2 >> 7, e = idx2 & 127;
        const float2 w2 = *(const float2*)(W + idx2);
        Wt[(e + 0) * 132 + d] = f2bf(w2.x);
        Wt[(e + 1) * 132 + d] = f2bf(w2.y);
    }
    __syncthreads();
    for (int idx8 = tid * 8; idx8 < DD * DD; idx8 += 2048) {
        const int e = idx8 >> 7, d = idx8 & 127;
        *(short8*)(o + idx8) = ld2x4(&Wt[e * 132 + d]);
    }
}

// ---------------------------------------------------------------------------
// Kernel A: projections v4. grid = (16 token-chunks, 16 heads, 3 tensors).
// Same compute as proj3 (LDS-staged W^T, conflict-free b128 reads); STORES
// differ: t=0 -> qA frag-major [jb][kk][32][16]; t=1 -> kp row-major;
// t=2 -> vpB frag-major [j16][d][16].
// ---------------------------------------------------------------------------
__global__ __launch_bounds__(256) void proj4_kernel(
    const float* __restrict__ q,
    const float* __restrict__ k,
    const float* __restrict__ v,
    const unsigned short* __restrict__ wsW,
    unsigned short* __restrict__ ws)
{
    __shared__ __align__(16) unsigned short Wt[128 * 136];  // [e][d], pitch 136
    const int t = blockIdx.z, h = blockIdx.y, cb = blockIdx.x;
    const int tid = threadIdx.x;
    const float* in = (t == 0) ? q : ((t == 1) ? k : v);
    const unsigned short* WTg = wsW + ((size_t)t * HN + h) * DD * DD;
    unsigned short* out = ws + (size_t)t * (HN * NN * DD) + (size_t)h * (NN * DD);

#pragma unroll
    for (int it = 0; it < 8; it++) {
        const int idx8 = tid * 8 + it * 2048;
        const int row = idx8 >> 7, col = idx8 & 127;
        *(short8*)(&Wt[row * 136 + col]) = *(const short8*)(WTg + idx8);
    }
    __syncthreads();

    const int wave = tid >> 6, lane = tid & 63;
    const int quad = lane >> 4, l16 = lane & 15;

#pragma unroll 1
    for (int rt = 0; rt < 2; rt++) {
        const int row0 = cb * 128 + rt * 64 + wave * 16;

        float4v acc[8];
#pragma unroll
        for (int c = 0; c < 8; c++) acc[c] = {0.f, 0.f, 0.f, 0.f};

        if (t < 2) {
#pragma unroll
            for (int kk = 0; kk < 4; kk++) {
                const short8 a = ld_bf8(in + (size_t)(row0 + l16) * DD + kk * 32 + quad * 8);
#pragma unroll
                for (int c = 0; c < 8; c++) {
                    const short8 b = *(const short8*)(&Wt[(c * 16 + l16) * 136 + kk * 32 + quad * 8]);
                    acc[c] = __builtin_amdgcn_mfma_f32_16x16x32_bf16(a, b, acc[c], 0, 0, 0);
                }
            }
            if (t == 0) {
                // qA[jb][kk=c][r32][16]: offset = ((row>>5)*8 + c)*512 + (row&31)*16 + l16
#pragma unroll
                for (int c = 0; c < 8; c++)
#pragma unroll
                    for (int r = 0; r < 4; r++) {
                        const int row = row0 + quad * 4 + r;
                        out[(size_t)(((row >> 5) * 8 + c)) * 512 + (row & 31) * 16 + l16]
                            = f2bf(acc[c][r]);
                    }
            } else {
                // kp row-major [n][d]
#pragma unroll
                for (int c = 0; c < 8; c++)
#pragma unroll
                    for (int r = 0; r < 4; r++)
                        out[(size_t)(row0 + quad * 4 + r) * DD + c * 16 + l16] = f2bf(acc[c][r]);
            }
        } else {
            // D[e][token] = vp^T via operand swap
#pragma unroll
            for (int kk = 0; kk < 4; kk++) {
                const short8 bv = ld_bf8(in + (size_t)(row0 + l16) * DD + kk * 32 + quad * 8);
#pragma unroll
                for (int c = 0; c < 8; c++) {
                    const short8 aw = *(const short8*)(&Wt[(c * 16 + l16) * 136 + kk * 32 + quad * 8]);
                    acc[c] = __builtin_amdgcn_mfma_f32_16x16x32_bf16(aw, bv, acc[c], 0, 0, 0);
                }
            }
            // vpB[jb16 = row0/16][d][j16 = l16]: offset = (row0>>4)*2048 + d*16 + l16
#pragma unroll
            for (int c = 0; c < 8; c++)
#pragma unroll
                for (int r = 0; r < 4; r++) {
                    const int d = c * 16 + quad * 4 + r;
                    out[(size_t)(row0 >> 4) * 2048 + d * 16 + l16] = f2bf(acc[c][r]);
                }
        }
    }
}

// ---------------------------------------------------------------------------
// Kernel B: flash attention, frag-major global operands, NO LDS / NO barriers
// in the main loop. grid = (32 i-tiles, 16 heads), 4 waves (ig, h2).
// Q reg-dbuf 1 tile ahead; V+mask issued at compute top; kp once per block.
// ---------------------------------------------------------------------------
__global__ __launch_bounds__(256, 2) void attn_kernel(
    unsigned short* __restrict__ ws,
    const unsigned long long* __restrict__ mbT)
{
    __shared__ __align__(16) float obuf[8192];   // epilogue partial-O combine
    __shared__ float lbuf[192];                  // epilogue row sums / inv

    const int h = blockIdx.y, ib = blockIdx.x;
    const int tid = threadIdx.x;
    const int wave = tid >> 6, lane = tid & 63;
    const int ig = wave >> 1;        // i-group: 0 -> rows 0..31, 1 -> 32..63
    const int h2 = wave & 1;         // j-half of each 64-j tile
    const int l31 = lane & 31;
    const int hi = lane >> 5;        // lane half

    const unsigned short* qA  = ws + (size_t)h * (NN * DD);                          // frag-major
    const unsigned short* kp  = ws + (size_t)(HN * NN * DD) + (size_t)h * (NN * DD); // row-major
    const unsigned short* vpB = ws + (size_t)(2 * HN * NN * DD) + (size_t)h * (NN * DD); // frag-major
    unsigned short* ao = ws + (size_t)(3 * HN * NN * DD);  // [N][H*D]

    const int i0 = ib * 64;
    const float scale = 0.022097086912079612f;  // 1/sqrt(2048)

    // kp B-frags (B[k=d][n=i], lane&31 = i): loaded once (gather ok: amortized).
    short8 kpf[8];
    {
        const int row = i0 + ig * 32 + l31;
#pragma unroll
        for (int kk = 0; kk < 8; kk++)
            kpf[kk] = *(const short8*)(kp + (size_t)row * DD + kk * 16 + hi * 8);
    }

    // per-lane base pointers into the frag-major arrays
    const unsigned short* qbase = qA + l31 * 16 + hi * 8;   // + (jb*8+kk)*512
    const unsigned short* vbase = vpB + l31 * 16 + hi * 8;  // + jb16*2048 + dt*512

    f32x16 o[4];
#pragma unroll
    for (int dt = 0; dt < 4; dt++)
#pragma unroll
        for (int r = 0; r < 16; r++) o[dt][r] = 0.f;
    float lacc = 0.f;

    short8 qfA[8], qfB[8];

#define QLD(QF, JT) do {                                                        \
        const unsigned short* p_ = qbase + (size_t)(((JT) * 2 + h2) * 8) * 512; \
        _Pragma("unroll")                                                       \
        for (int kk = 0; kk < 8; kk++)                                          \
            QF[kk] = *(const short8*)(p_ + kk * 512);                           \
    } while (0)

    // T[j][i] = sum_d qp[j][d]*kp[i][d]: A = qf (regs), B = kpf (regs).
    // C/D: col = lane&31 = i, row j = CROW(r) + 4*hi (+ h2*32 in tile).
    auto COMPUTE = [&](const short8 (&qf)[8], int jt) {
        // V B-frags: 8 contiguous-1KB wave-loads; consumed after QK+softmax.
        short8 vf[8];
#pragma unroll
        for (int ks = 0; ks < 2; ks++)
#pragma unroll
            for (int dt = 0; dt < 4; dt++)
                vf[ks * 4 + dt] = *(const short8*)(vbase
                    + (size_t)(jt * 4 + h2 * 2 + ks) * 2048 + dt * 512);
        // mask word: coalesced 256B (mbT transposed)
        const unsigned long long mrow = mbT[(size_t)jt * NN + i0 + ig * 32 + l31];
        const unsigned int m2 = (unsigned int)(mrow >> (h2 * 32 + hi * 4));

        f32x16 s;
#pragma unroll
        for (int r = 0; r < 16; r++) s[r] = 0.f;
        __builtin_amdgcn_s_setprio(1);
#pragma unroll
        for (int kk = 0; kk < 8; kk++)
            s = __builtin_amdgcn_mfma_f32_32x32x16_bf16(qf[kk], kpf[kk], s, 0, 0, 0);
        __builtin_amdgcn_s_setprio(0);

        // static-max softmax: p = exp(s*scale - 5) (masked -> exp(-50) ~ 0)
#pragma unroll
        for (int r = 0; r < 16; r++) {
            const float x = ((m2 >> CROW(r)) & 1u) ? fmaf(s[r], scale, -5.0f) : -50.0f;
            s[r] = __expf(x);
        }
        // row-sum over this j-tile for denominator (i = lane&31)
        float ls = (((s[0] + s[1]) + (s[2] + s[3])) + ((s[4] + s[5]) + (s[6] + s[7])))
                 + (((s[8] + s[9]) + (s[10] + s[11])) + ((s[12] + s[13]) + (s[14] + s[15])));
        ls += __shfl_xor(ls, 32);
        lacc += ls;

        // T12 repack: P -> two PV A-frags (lane = i, k = j), zero LDS.
        short8 pa[2];
#pragma unroll
        for (int ks = 0; ks < 2; ks++) {
            const int b = ks * 8;
            unsigned int x0 = cvtpk(s[b + 0], s[b + 1]);
            unsigned int y0 = cvtpk(s[b + 4], s[b + 5]);
            unsigned int x1 = cvtpk(s[b + 2], s[b + 3]);
            unsigned int y1 = cvtpk(s[b + 6], s[b + 7]);
            plswap(x0, y0);
            plswap(x1, y1);
            uint4v w; w[0] = x0; w[1] = x1; w[2] = y0; w[3] = y1;
            pa[ks] = __builtin_bit_cast(short8, w);
        }

        // O[i][d] += P · vp
        __builtin_amdgcn_s_setprio(1);
#pragma unroll
        for (int ks = 0; ks < 2; ks++)
#pragma unroll
            for (int dt = 0; dt < 4; dt++)
                o[dt] = __builtin_amdgcn_mfma_f32_32x32x16_bf16(pa[ks], vf[ks * 4 + dt], o[dt], 0, 0, 0);
        __builtin_amdgcn_s_setprio(0);
    };

    QLD(qfA, 0);
#pragma unroll 1
    for (int jt = 0; jt < 32; jt += 2) {
        QLD(qfB, jt + 1);
        COMPUTE(qfA, jt);
        if (jt + 2 < 32) QLD(qfA, jt + 2);
        COMPUTE(qfB, jt + 1);
    }
#undef QLD

    // Epilogue: combine partner-wave partials (same ig, other j-half) via LDS.
    if (h2 == 1) {
#pragma unroll
        for (int dt = 0; dt < 4; dt++)
#pragma unroll
            for (int r = 0; r < 16; r++)
                obuf[(((ig * 2 + hi) * 4 + dt) * 16 + r) * 32 + l31] = o[dt][r];
        if (hi == 0) lbuf[ig * 32 + l31] = lacc;
    }
    __syncthreads();
    if (h2 == 0) {
        const float lt = lacc + lbuf[ig * 32 + l31];
        const float inv = (lt > 0.f) ? (1.0f / lt) : 0.f;
        if (hi == 0) lbuf[64 + ig * 32 + l31] = inv;  // same-wave RAW, lgkm-ordered
#pragma unroll
        for (int dt = 0; dt < 4; dt++)
#pragma unroll
            for (int r = 0; r < 16; r++) {
                const int row = CROW(r) + hi * 4;     // i_local 0..31
                const float val = (o[dt][r] + obuf[(((ig * 2 + hi) * 4 + dt) * 16 + r) * 32 + l31])
                                  * lbuf[64 + ig * 32 + row];
                ao[(size_t)(i0 + ig * 32 + row) * (HN * DD) + h * DD + dt * 32 + l31] = f2bf(val);
            }
    }
}

// ---------------------------------------------------------------------------
// Kernel C: final GEMM [2048,2048]x[2048,128] -> f32, K-split x4.
// ---------------------------------------------------------------------------
__global__ __launch_bounds__(256) void final2_kernel(
    const unsigned short* __restrict__ ao,
    const float* __restrict__ last,
    float* __restrict__ outp)
{
    __shared__ __align__(16) unsigned short lt[32 * 516];  // [e_local][k_local]
    const int tid = threadIdx.x;
    const int wave = tid >> 6, lane = tid & 63;
    const int quad = lane >> 4, l16 = lane & 15;
    const int i0 = blockIdx.x * 64;
    const int e0 = blockIdx.y * 32;
    const int k0 = blockIdx.z * 512;

#pragma unroll
    for (int idx2 = tid * 2; idx2 < 512 * 32; idx2 += 512) {
        const int kk = idx2 >> 5, e = idx2 & 31;
        const float2 w2 = *(const float2*)(last + (size_t)(k0 + kk) * DD + e0 + e);
        lt[(e + 0) * 516 + kk] = f2bf(w2.x);
        lt[(e + 1) * 516 + kk] = f2bf(w2.y);
    }
    __syncthreads();

    float4v acc[2];
    acc[0] = {0.f, 0.f, 0.f, 0.f};
    acc[1] = {0.f, 0.f, 0.f, 0.f};

    const unsigned short* arow = ao + (size_t)(i0 + wave * 16 + l16) * (HN * DD) + k0;

#pragma unroll
    for (int kb = 0; kb < 8; kb++) {
#pragma unroll
        for (int ks = 0; ks < 2; ks++) {
            const short8 a = *(const short8*)(arow + kb * 64 + ks * 32 + quad * 8);
#pragma unroll
            for (int dc = 0; dc < 2; dc++) {
                const short8 b = ld2x4(&lt[(dc * 16 + l16) * 516 + kb * 64 + ks * 32 + quad * 8]);
                acc[dc] = __builtin_amdgcn_mfma_f32_16x16x32_bf16(a, b, acc[dc], 0, 0, 0);
            }
        }
    }

#pragma unroll
    for (int r = 0; r < 4; r++)
#pragma unroll
        for (int dc = 0; dc < 2; dc++)
            atomicAdd(&outp[(size_t)(i0 + wave * 16 + quad * 4 + r) * DD + e0 + dc * 16 + l16],
                      acc[dc][r]);
}

extern "C" void kernel_launch(void* const* d_in, const int* in_sizes, int n_in,
                              void* d_out, int out_size, void* d_ws, size_t ws_size,
                              hipStream_t stream)
{
    const float* q    = (const float*)d_in[0];
    const float* k    = (const float*)d_in[1];
    const float* v    = (const float*)d_in[2];
    const int*   mask = (const int*)d_in[3];
    const float* Qw   = (const float*)d_in[4];
    const float* Kw   = (const float*)d_in[5];
    const float* Vw   = (const float*)d_in[6];
    const float* last = (const float*)d_in[7];
    unsigned short* ws  = (unsigned short*)d_ws;
    float* out = (float*)d_out;

    // ws (bf16): qA[16*2048*128] | kp[...] | vpB[16][...] | ao[2048][2048]
    //            | mbT[32][2048] u64 (bitpacked mask, transposed)
    // wsW (bf16 W^T, 1.5MB) lives INSIDE the ao region (dead until attn).
    const size_t shorts_main = (size_t)4 * HN * NN * DD;   // qA+kp+vpB+ao
    const size_t mb_bytes = (size_t)NN * (NN / 64) * 8;
    const size_t needed = shorts_main * sizeof(unsigned short) + mb_bytes;
    if (ws_size < needed) {
        sentinel_kernel<<<(out_size + 255) / 256, 256, 0, stream>>>(out, out_size);
        return;
    }
    unsigned long long* mbT = (unsigned long long*)(ws + shorts_main);
    unsigned short* wsW = ws + (size_t)3 * HN * NN * DD;   // = ao region

    maskpack2_kernel<<<dim3(NN * (NN / 64) / 16), 256, 0, stream>>>(mask, mbT, out, out_size);
    wprep_kernel<<<dim3(16, 3), 256, 0, stream>>>(Qw, Kw, Vw, wsW);
    proj4_kernel<<<dim3(16, 16, 3), 256, 0, stream>>>(q, k, v, wsW, ws);
    attn_kernel<<<dim3(32, 16), 256, 0, stream>>>(ws, mbT);
    final2_kernel<<<dim3(32, 4, 4), 256, 0, stream>>>(ws + (size_t)3 * HN * NN * DD, last, out);
}